// Round 18
// baseline (389.752 us; speedup 1.0000x reference)
//
#include <hip/hip_runtime.h>

#define T_ 32
#define B_ 32
#define S_ 64
#define C_ 1024
#define H_ 1024
#define HSLOT 32768   // ushorts per h ring slot / per x_t slab (32 x 1024)
#define NXCD 8

typedef __attribute__((ext_vector_type(8))) short bf16x8;
typedef __attribute__((ext_vector_type(4))) float f32x4;

// d_out layout (float offsets): outputs[32*32*1024], h[32*1024], c[32*1024], attn[32*32*64]
#define OUT_H   1048576
#define OUT_CC  1081344
#define OUT_AT  1114112

__device__ __forceinline__ ushort f2b(float f) {
  unsigned u = __float_as_uint(f);
  unsigned r = (u + 0x7FFFu + ((u >> 16) & 1u)) >> 16;
  return (ushort)r;
}
__device__ __forceinline__ float b2f(ushort h) {
  return __uint_as_float(((unsigned)h) << 16);
}

// ---- init: cvt inp -> bf16; v = W2@W1_x; bias; zero slot0 of all 8 XCD rings; zero flags+ctr ----
__global__ __launch_bounds__(256) void k_init(const float* __restrict__ inp, ushort* __restrict__ inpb,
                                              const float* __restrict__ W1, const float* __restrict__ W2,
                                              const float* __restrict__ bih, const float* __restrict__ bhh,
                                              float* __restrict__ v, float* __restrict__ bias,
                                              ushort* __restrict__ hring, unsigned* __restrict__ flags) {
  int blk = blockIdx.x, tid = threadIdx.x;
  if (blk < 512) {
    size_t i = ((size_t)blk * 256 + tid) * 8;
    float4 v0 = *reinterpret_cast<const float4*>(inp + i);
    float4 v1 = *reinterpret_cast<const float4*>(inp + i + 4);
    uint4 o;
    o.x = (unsigned)f2b(v0.x) | ((unsigned)f2b(v0.y) << 16);
    o.y = (unsigned)f2b(v0.z) | ((unsigned)f2b(v0.w) << 16);
    o.z = (unsigned)f2b(v1.x) | ((unsigned)f2b(v1.y) << 16);
    o.w = (unsigned)f2b(v1.z) | ((unsigned)f2b(v1.w) << 16);
    *reinterpret_cast<uint4*>(inpb + i) = o;
  } else if (blk < 516) {
    int c = (blk - 512) * 256 + tid;
    float acc = 0.f;
#pragma unroll 8
    for (int a = 0; a < 128; ++a) acc += W1[a * 2048 + 1024 + c] * W2[a];
    v[c] = acc;
  } else if (blk < 532) {
    int jj = (blk - 516) * 256 + tid;
    bias[jj] = bih[jj] + bhh[jj];
  } else if (blk < 564) {
    // zero slot 0 of each XCD ring: 8 x 16384 u32 = 131072 u32 over 32 blocks
    int base = (blk - 532) * 4096;
    for (int i = 0; i < 16; ++i) {
      int idx = base + i * 256 + tid;
      int xcd = idx >> 14, off = idx & 16383;
      reinterpret_cast<unsigned*>(hring + (size_t)xcd * 33 * HSLOT)[off] = 0u;
    }
  } else {
    // zero 4096 flag words + 8 rank counters
    for (int i = 0; i < 17; ++i) {
      int idx = i * 256 + tid;
      if (idx < 4104) flags[idx] = 0u;
    }
  }
}

// ---- cooperative kernel: 256 WGs x 1024 threads, 1 WG/CU (LDS>80KB forces it) ----
// Each XCD (HW_REG_XCC_ID) hosts exactly 32 WGs (pigeonhole at 1 WG/CU) and runs the FULL
// recurrence independently: h exchanged through the XCD-local L2 via plain stores/loads on an
// XCD-private 33-slot ring (each slot written once per launch). Only the 4B flags use agent
// scope. xpT writes are PURE values (K-halves combined in LDS first) -> cross-XCD duplicate
// writes are bit-identical and race-benign; each XCD reads back its own WG's writes.
__global__ __launch_bounds__(1024, 4) void k_rec(const float* __restrict__ Wih, const float* __restrict__ Whh,
                                                 const ushort* __restrict__ inpb, ushort* __restrict__ hring,
                                                 const float* __restrict__ ctx, const float* __restrict__ v,
                                                 const float* __restrict__ bias, float* __restrict__ out,
                                                 unsigned* __restrict__ flags, ushort* __restrict__ xpT) {
  int tid = threadIdx.x, lane = tid & 63, w = tid >> 6;
  __shared__ uint4 hl4[4096];            // 64 KB staging: idx = row*128 + (c16 ^ (row&7))
  __shared__ float red[8][2][17][33];    // ~35 KB K-partials (padded vs bank conflicts)
  __shared__ float v_s[1024];
  __shared__ float sc_s[64];
  __shared__ float att_s[64];
  __shared__ float4 wgt_s[32];
  __shared__ unsigned rank_s;

  unsigned xcd;
  asm volatile("s_getreg_b32 %0, hwreg(HW_REG_XCC_ID)" : "=s"(xcd));
  xcd &= 7u;
  if (tid == 0) rank_s = atomicAdd(&flags[4096 + xcd], 1u) & 31u;
  __syncthreads();
  int rank = (int)rank_s;
  int hid0 = rank * 32;
  ushort* hring_x = hring + (size_t)xcd * 33 * HSLOT;

  // ================= attention: batch b=rank, column-slice = xcd =================
  v_s[tid] = v[tid];
  __syncthreads();
  {
    int s = w * 4;
#pragma unroll
    for (int si = 0; si < 4; ++si, ++s) {
      const float* xr = ctx + (size_t)(s * B_ + rank) * C_;
      float acc = 0.f;
#pragma unroll
      for (int i = 0; i < 16; ++i) { int c = lane + i * 64; acc += xr[c] * v_s[c]; }
      for (int off = 32; off; off >>= 1) acc += __shfl_down(acc, off);
      if (lane == 0) sc_s[s] = acc;
    }
  }
  __syncthreads();
  if (tid < 64) {
    float val = sc_s[tid];
    float mx = val;
    for (int off = 32; off; off >>= 1) mx = fmaxf(mx, __shfl_xor(mx, off));
    float e = expf(val - mx);
    float sm = e;
    for (int off = 32; off; off >>= 1) sm += __shfl_xor(sm, off);
    att_s[tid] = e / sm;
  }
  __syncthreads();
  if (tid < 32) {
    const float4* ctx4 = reinterpret_cast<const float4*>(ctx);
    float4 a4 = {0.f, 0.f, 0.f, 0.f};
    for (int s = 0; s < 64; ++s) {
      float a = att_s[s];
      float4 x = ctx4[(size_t)(s * B_ + rank) * 256 + xcd * 32 + tid];
      a4.x += a * x.x; a4.y += a * x.y; a4.z += a * x.z; a4.w += a * x.w;
    }
    wgt_s[tid] = a4;
  }
  __syncthreads();
  {
    int t = tid >> 5, c4 = tid & 31;
    reinterpret_cast<float4*>(out)[(size_t)(t * B_ + rank) * 256 + xcd * 32 + c4] = wgt_s[c4];
  }
  if (tid < 64) {
    float av = att_s[tid];
#pragma unroll 4
    for (int t = 0; t < T_; ++t) out[OUT_AT + (t * B_ + rank) * 64 + tid] = av;
  }

  // wave decomposition: 16 waves = 8 row-tiles x 2 K-halves
  int tq = w >> 1, ks = w & 1;
  int g = lane >> 4, r = lane & 15;
  int jrow = (r >> 2) * 1024 + hid0 + tq * 4 + (r & 3);

  // epilogue cell: thread owns (batch eb = tid>>5, hidL = tid&31)
  int eb = tid >> 5, ehl = tid & 31;
  int ehidx = hid0 + ehl;
  int etq = ehl >> 2, er = ehl & 3;

  // ================= x-projection (pure writes; K-halves combined in LDS) =================
  {
    bf16x8 ax[16];
    const float* ap = Wih + (size_t)jrow * 1024 + ks * 512 + g * 8;
#pragma unroll
    for (int kk = 0; kk < 16; ++kk) {
      float4 f0 = *reinterpret_cast<const float4*>(ap + kk * 32);
      float4 f1 = *reinterpret_cast<const float4*>(ap + kk * 32 + 4);
      bf16x8 t8;
      t8[0] = (short)f2b(f0.x); t8[1] = (short)f2b(f0.y);
      t8[2] = (short)f2b(f0.z); t8[3] = (short)f2b(f0.w);
      t8[4] = (short)f2b(f1.x); t8[5] = (short)f2b(f1.y);
      t8[6] = (short)f2b(f1.z); t8[7] = (short)f2b(f1.w);
      ax[kk] = t8;
    }
#pragma unroll 1
    for (int mc = 0; mc < 32; ++mc) {
      __syncthreads();  // red from previous iteration fully consumed
      {
        const uint4* s4 = reinterpret_cast<const uint4*>(inpb + (size_t)mc * HSLOT);
        uint4 v0 = s4[tid], v1 = s4[tid + 1024], v2 = s4[tid + 2048], v3 = s4[tid + 3072];
        int c0 = tid, c1 = tid + 1024, c2 = tid + 2048, c3 = tid + 3072;
        hl4[(c0 >> 7) * 128 + ((c0 & 127) ^ ((c0 >> 7) & 7))] = v0;
        hl4[(c1 >> 7) * 128 + ((c1 & 127) ^ ((c1 >> 7) & 7))] = v1;
        hl4[(c2 >> 7) * 128 + ((c2 & 127) ^ ((c2 >> 7) & 7))] = v2;
        hl4[(c3 >> 7) * 128 + ((c3 & 127) ^ ((c3 >> 7) & 7))] = v3;
      }
      __syncthreads();
      f32x4 a0 = (f32x4)(0.f), a1 = (f32x4)(0.f);
#pragma unroll
      for (int kk = 0; kk < 16; ++kk) {
        int c16 = ks * 64 + kk * 4 + g;
        bf16x8 b0 = *reinterpret_cast<const bf16x8*>(&hl4[r * 128 + (c16 ^ (r & 7))]);
        bf16x8 b1 = *reinterpret_cast<const bf16x8*>(&hl4[(r + 16) * 128 + (c16 ^ (r & 7))]);
        a0 = __builtin_amdgcn_mfma_f32_16x16x32_bf16(ax[kk], b0, a0, 0, 0, 0);
        a1 = __builtin_amdgcn_mfma_f32_16x16x32_bf16(ax[kk], b1, a1, 0, 0, 0);
      }
#pragma unroll
      for (int e = 0; e < 4; ++e) {
        red[tq][ks][g * 4 + e][r] = a0[e];
        red[tq][ks][g * 4 + e][r + 16] = a1[e];
      }
      __syncthreads();
      // combine K-halves, pack 4 gates, ONE pure global write per thread (bit-identical across XCDs)
      {
        int m = mc * 32 + eb;
        ushort4 xv;
        xv.x = f2b(red[etq][0][er][eb]      + red[etq][1][er][eb]);
        xv.y = f2b(red[etq][0][4 + er][eb]  + red[etq][1][4 + er][eb]);
        xv.z = f2b(red[etq][0][8 + er][eb]  + red[etq][1][8 + er][eb]);
        xv.w = f2b(red[etq][0][12 + er][eb] + red[etq][1][12 + er][eb]);
        *reinterpret_cast<ushort4*>(xpT + ((size_t)m * 1024 + ehidx) * 4) = xv;
      }
    }
    asm volatile("s_waitcnt vmcnt(0)" ::: "memory");
    __syncthreads();  // xpT (own WG's cells) drained to L2 before the recurrence reads them
  }

  // ================= load W_hh fragments (f32 -> bf16 in-register) =================
  bf16x8 ah[16];
  {
    const float* ap = Whh + (size_t)jrow * 1024 + ks * 512 + g * 8;
#pragma unroll
    for (int kk = 0; kk < 16; ++kk) {
      float4 f0 = *reinterpret_cast<const float4*>(ap + kk * 32);
      float4 f1 = *reinterpret_cast<const float4*>(ap + kk * 32 + 4);
      bf16x8 t8;
      t8[0] = (short)f2b(f0.x); t8[1] = (short)f2b(f0.y);
      t8[2] = (short)f2b(f0.z); t8[3] = (short)f2b(f0.w);
      t8[4] = (short)f2b(f1.x); t8[5] = (short)f2b(f1.y);
      t8[6] = (short)f2b(f1.z); t8[7] = (short)f2b(f1.w);
      ah[kk] = t8;
    }
  }

  float bs0 = bias[ehidx], bs1 = bias[1024 + ehidx], bs2 = bias[2048 + ehidx], bs3 = bias[3072 + ehidx];
  float c_reg = 0.f;

  // ================= recurrence: XCD-local =================
#pragma unroll 1
  for (int t = 0; t < T_; ++t) {
    if (t > 0 && w == 0) {
      for (;;) {
        unsigned vf = __hip_atomic_load(&flags[(xcd * 32 + (lane & 31)) * 16], __ATOMIC_RELAXED, __HIP_MEMORY_SCOPE_AGENT);
        if (__all((int)(vf >= (unsigned)t))) break;
        __builtin_amdgcn_s_sleep(1);
      }
    }
    __syncthreads();
    {
      const uint4* s4 = reinterpret_cast<const uint4*>(hring_x + (size_t)t * HSLOT);
      uint4 v0 = s4[tid], v1 = s4[tid + 1024], v2 = s4[tid + 2048], v3 = s4[tid + 3072];
      int c0 = tid, c1 = tid + 1024, c2 = tid + 2048, c3 = tid + 3072;
      hl4[(c0 >> 7) * 128 + ((c0 & 127) ^ ((c0 >> 7) & 7))] = v0;
      hl4[(c1 >> 7) * 128 + ((c1 & 127) ^ ((c1 >> 7) & 7))] = v1;
      hl4[(c2 >> 7) * 128 + ((c2 & 127) ^ ((c2 >> 7) & 7))] = v2;
      hl4[(c3 >> 7) * 128 + ((c3 & 127) ^ ((c3 >> 7) & 7))] = v3;
    }
    __syncthreads();
    f32x4 a0 = (f32x4)(0.f), a1 = (f32x4)(0.f);
#pragma unroll
    for (int kk = 0; kk < 16; ++kk) {
      int c16 = ks * 64 + kk * 4 + g;
      bf16x8 b0 = *reinterpret_cast<const bf16x8*>(&hl4[r * 128 + (c16 ^ (r & 7))]);
      bf16x8 b1 = *reinterpret_cast<const bf16x8*>(&hl4[(r + 16) * 128 + (c16 ^ (r & 7))]);
      a0 = __builtin_amdgcn_mfma_f32_16x16x32_bf16(ah[kk], b0, a0, 0, 0, 0);
      a1 = __builtin_amdgcn_mfma_f32_16x16x32_bf16(ah[kk], b1, a1, 0, 0, 0);
    }
#pragma unroll
    for (int e = 0; e < 4; ++e) {
      red[tq][ks][g * 4 + e][r] = a0[e];
      red[tq][ks][g * 4 + e][r + 16] = a1[e];
    }
    __syncthreads();
    {
      int m = t * 32 + eb;
      ushort4 xv = *reinterpret_cast<const ushort4*>(xpT + ((size_t)m * 1024 + ehidx) * 4);
      float ig = red[etq][0][er][eb]      + red[etq][1][er][eb]      + b2f(xv.x) + bs0;
      float fg = red[etq][0][4 + er][eb]  + red[etq][1][4 + er][eb]  + b2f(xv.y) + bs1;
      float gg = red[etq][0][8 + er][eb]  + red[etq][1][8 + er][eb]  + b2f(xv.z) + bs2;
      float og = red[etq][0][12 + er][eb] + red[etq][1][12 + er][eb] + b2f(xv.w) + bs3;
      float si = 1.f / (1.f + __expf(-ig));
      float sf = 1.f / (1.f + __expf(-fg));
      float so = 1.f / (1.f + __expf(-og));
      float c_new = sf * c_reg + si * tanhf(gg);
      float h_new = so * tanhf(c_new);
      c_reg = c_new;
      if (t < T_ - 1) {
        hring_x[(size_t)(t + 1) * HSLOT + eb * 1024 + ehidx] = f2b(h_new);  // plain store -> local L2
      } else {
        out[OUT_H + eb * 1024 + ehidx] = h_new;
        out[OUT_CC + eb * 1024 + ehidx] = c_new;
      }
    }
    asm volatile("s_waitcnt vmcnt(0)" ::: "memory");
    __syncthreads();  // all h stores of the WG are in local L2 now
    if (t < T_ - 1 && w == 0 && lane == 0)
      __hip_atomic_store(&flags[(xcd * 32 + rank) * 16], (unsigned)(t + 1), __ATOMIC_RELAXED, __HIP_MEMORY_SCOPE_AGENT);
  }
}

extern "C" void kernel_launch(void* const* d_in, const int* in_sizes, int n_in,
                              void* d_out, int out_size, void* d_ws, size_t ws_size,
                              hipStream_t stream) {
  const float* inp = (const float*)d_in[0];
  const float* ctx = (const float*)d_in[1];
  const float* Wih = (const float*)d_in[2];
  const float* Whh = (const float*)d_in[3];
  const float* bih = (const float*)d_in[4];
  const float* bhh = (const float*)d_in[5];
  const float* W1  = (const float*)d_in[6];
  const float* W2  = (const float*)d_in[8];
  float* out = (float*)d_out;
  char* wsb = (char*)d_ws;

  float* v      = (float*)(wsb + 0);           // 4 KB
  float* bias   = (float*)(wsb + 4096);        // 16 KB
  unsigned* flags = (unsigned*)(wsb + 20480);  // 4096 flag words + 8 counters (~16.5 KB)
  ushort* inpb  = (ushort*)(wsb + 40960);      // 2 MB
  ushort* xpT   = (ushort*)(wsb + 2138112);    // 8 MB  [m][hid][gate] bf16
  ushort* hring = (ushort*)(wsb + 10526720);   // 8 XCDs x 33 slots x 64 KB = 16.5 MB
  // end ~27.9 MB

  hipLaunchKernelGGL(k_init, dim3(565), dim3(256), 0, stream,
                     inp, inpb, W1, W2, bih, bhh, v, bias, hring, flags);

  const float* Wih_c = Wih;
  const float* Whh_c = Whh;
  const ushort* inpb_c = inpb;
  const float* ctx_c = ctx;
  const float* v_c = v;
  const float* bias_c = bias;
  void* kargs[10];
  kargs[0] = (void*)&Wih_c;
  kargs[1] = (void*)&Whh_c;
  kargs[2] = (void*)&inpb_c;
  kargs[3] = (void*)&hring;
  kargs[4] = (void*)&ctx_c;
  kargs[5] = (void*)&v_c;
  kargs[6] = (void*)&bias_c;
  kargs[7] = (void*)&out;
  kargs[8] = (void*)&flags;
  kargs[9] = (void*)&xpT;
  hipLaunchCooperativeKernel((const void*)k_rec, dim3(256), dim3(1024), kargs, 0, stream);
}

// Round 19
// 269.941 us; speedup vs baseline: 1.4438x; 1.4438x over previous
//
#include <hip/hip_runtime.h>

#define T_ 32
#define B_ 32
#define S_ 64
#define C_ 1024
#define H_ 1024
#define NWG 64
#define HSLOT 32768  // ushorts per h ring slot / x_t slab

typedef __attribute__((ext_vector_type(8))) short bf16x8;
typedef __attribute__((ext_vector_type(4))) float f32x4;

// d_out layout (float offsets): outputs[32*32*1024], h[32*1024], c[32*1024], attn[32*32*64]
#define OUT_H   1048576
#define OUT_CC  1081344
#define OUT_AT  1114112

__device__ __forceinline__ ushort f2b(float f) {
  unsigned u = __float_as_uint(f);
  unsigned r = (u + 0x7FFFu + ((u >> 16) & 1u)) >> 16;
  return (ushort)r;
}
__device__ __forceinline__ float b2f(ushort h) {
  return __uint_as_float(((unsigned)h) << 16);
}

// ---- init: cvt inp + Wih to bf16; zero hring slot0; zero flags ----
__global__ __launch_bounds__(256) void k_init(const float* __restrict__ inp, ushort* __restrict__ inpb,
                                              const float* __restrict__ Wih, ushort* __restrict__ Wihb,
                                              ushort* __restrict__ hring, unsigned* __restrict__ flags) {
  int blk = blockIdx.x, tid = threadIdx.x;
  if (blk < 2560) {
    const float* src; ushort* dst; int base;
    if (blk < 512) { src = inp; dst = inpb; base = blk; }
    else { src = Wih; dst = Wihb; base = blk - 512; }
    size_t i = ((size_t)base * 256 + tid) * 8;
    float4 v0 = *reinterpret_cast<const float4*>(src + i);
    float4 v1 = *reinterpret_cast<const float4*>(src + i + 4);
    uint4 o;
    o.x = (unsigned)f2b(v0.x) | ((unsigned)f2b(v0.y) << 16);
    o.y = (unsigned)f2b(v0.z) | ((unsigned)f2b(v0.w) << 16);
    o.z = (unsigned)f2b(v1.x) | ((unsigned)f2b(v1.y) << 16);
    o.w = (unsigned)f2b(v1.z) | ((unsigned)f2b(v1.w) << 16);
    *reinterpret_cast<uint4*>(dst + i) = o;
  } else if (blk < 2564) {
    unsigned* hz = reinterpret_cast<unsigned*>(hring);
    int base = (blk - 2560) * 4096;
    for (int i = 0; i < 16; ++i) hz[base + i * 256 + tid] = 0u;
  } else {
    for (int i = 0; i < 8; ++i) flags[i * 256 + tid] = 0u;
  }
}

// ---- cooperative kernel: 224 WGs x 1024 threads ----
// WGs 0..63   : persistent recurrence (r8 step structure; xpT consumed via xflag gating)
// WGs 64..95  : attention (computes v itself) + outputs/attn broadcast; exit
// WGs 96..223 : x-projection producers: WG j -> timestep t=(j-96)>>2, gate=(j-96)&3;
//               publish xpT slab via agent-scope stores + atomicAdd(xflag[t]); exit
__global__ __launch_bounds__(1024, 4) void k_rec(const float* __restrict__ Whh, const ushort* __restrict__ Wihb,
                                                 const ushort* __restrict__ inpb, ushort* __restrict__ hring,
                                                 const float* __restrict__ ctx,
                                                 const float* __restrict__ W1, const float* __restrict__ W2,
                                                 const float* __restrict__ bih, const float* __restrict__ bhh,
                                                 float* __restrict__ out, unsigned* __restrict__ flags,
                                                 ushort* __restrict__ xpT) {
  int tid = threadIdx.x, lane = tid & 63, w = tid >> 6;
  int wg = blockIdx.x;

  __shared__ uint4 hl4[4096];           // 64 KB staging: idx = row*128 + (c16 ^ (row&7))
  __shared__ float red[4][4][16][32];   // 32 KB K-slice partials
  __shared__ __align__(16) ushort hs[32][16];
  __shared__ float v_s[1024];
  __shared__ float sc_s[64];
  __shared__ float att_s[64];

  if (wg >= NWG + 32) {
    // ================= x-projection producer =================
    int j = wg - (NWG + 32);
    int t = j >> 2, gate = j & 3;
    // stage x_t
    {
      const uint4* s4 = reinterpret_cast<const uint4*>(inpb + (size_t)t * HSLOT);
      uint4 v0 = s4[tid], v1 = s4[tid + 1024], v2 = s4[tid + 2048], v3 = s4[tid + 3072];
      int c0 = tid, c1 = tid + 1024, c2 = tid + 2048, c3 = tid + 3072;
      hl4[(c0 >> 7) * 128 + ((c0 & 127) ^ ((c0 >> 7) & 7))] = v0;
      hl4[(c1 >> 7) * 128 + ((c1 & 127) ^ ((c1 >> 7) & 7))] = v1;
      hl4[(c2 >> 7) * 128 + ((c2 & 127) ^ ((c2 >> 7) & 7))] = v2;
      hl4[(c3 >> 7) * 128 + ((c3 & 127) ^ ((c3 >> 7) & 7))] = v3;
    }
    __syncthreads();
    int g = lane >> 4, r = lane & 15;
    f32x4 acc[2][4];
#pragma unroll
    for (int a = 0; a < 2; ++a)
#pragma unroll
      for (int b = 0; b < 4; ++b) acc[a][b] = (f32x4)(0.f);
#pragma unroll 4
    for (int kstep = 0; kstep < 32; ++kstep) {
      int c16 = kstep * 4 + g;
      bf16x8 af0 = *reinterpret_cast<const bf16x8*>(&hl4[r * 128 + (c16 ^ (r & 7))]);
      bf16x8 af1 = *reinterpret_cast<const bf16x8*>(&hl4[(16 + r) * 128 + (c16 ^ (r & 7))]);
#pragma unroll
      for (int hq = 0; hq < 4; ++hq) {
        int hid = w * 64 + hq * 16 + r;
        bf16x8 bw = *reinterpret_cast<const bf16x8*>(Wihb + (size_t)(gate * 1024 + hid) * 1024 + kstep * 32 + g * 8);
        acc[0][hq] = __builtin_amdgcn_mfma_f32_16x16x32_bf16(af0, bw, acc[0][hq], 0, 0, 0);
        acc[1][hq] = __builtin_amdgcn_mfma_f32_16x16x32_bf16(af1, bw, acc[1][hq], 0, 0, 0);
      }
    }
    __syncthreads();  // x reads done; reuse hl4 as bf16 [b(32)][hid(1024)]
    {
      ushort* xs = reinterpret_cast<ushort*>(hl4);
      int q = lane >> 4;
#pragma unroll
      for (int bh = 0; bh < 2; ++bh)
#pragma unroll
        for (int hq = 0; hq < 4; ++hq)
#pragma unroll
          for (int e = 0; e < 4; ++e)
            xs[(bh * 16 + q * 4 + e) * 1024 + w * 64 + hq * 16 + r] = f2b(acc[bh][hq][e]);
    }
    __syncthreads();
    // coalesced agent-scope publish: thread owns (b = tid>>5, 32-hid chunk k = tid&31)
    {
      const unsigned long long* xs8 = reinterpret_cast<const unsigned long long*>(hl4);
      int b = tid >> 5, k = tid & 31;
      unsigned long long* dst = reinterpret_cast<unsigned long long*>(
          xpT + ((size_t)(t * 32 + b) * 4 + gate) * 1024 + k * 32);
#pragma unroll
      for (int i = 0; i < 8; ++i) {
        unsigned long long val = xs8[b * 256 + k * 8 + i];
        __hip_atomic_store(dst + i, val, __ATOMIC_RELAXED, __HIP_MEMORY_SCOPE_AGENT);
      }
    }
    asm volatile("s_waitcnt vmcnt(0)" ::: "memory");
    __syncthreads();
    if (tid == 0)
      __hip_atomic_fetch_add(&flags[1024 + t], 1u, __ATOMIC_RELAXED, __HIP_MEMORY_SCOPE_AGENT);
    return;
  }

  if (wg >= NWG) {
    // ================= attention path (batch b = wg-64) =================
    int b = wg - NWG;
    {
      float acc = 0.f;
#pragma unroll 8
      for (int a = 0; a < 128; ++a) acc += W1[a * 2048 + 1024 + tid] * W2[a];
      v_s[tid] = acc;
    }
    __syncthreads();
    {
      int s = w * 4;
#pragma unroll
      for (int si = 0; si < 4; ++si, ++s) {
        const float* xr = ctx + (size_t)(s * B_ + b) * C_;
        float acc = 0.f;
#pragma unroll
        for (int i = 0; i < 16; ++i) { int c = lane + i * 64; acc += xr[c] * v_s[c]; }
        for (int off = 32; off; off >>= 1) acc += __shfl_down(acc, off);
        if (lane == 0) sc_s[s] = acc;
      }
    }
    __syncthreads();
    if (tid < 64) {
      float val = sc_s[tid];
      float mx = val;
      for (int off = 32; off; off >>= 1) mx = fmaxf(mx, __shfl_xor(mx, off));
      float e = expf(val - mx);
      float sm = e;
      for (int off = 32; off; off >>= 1) sm += __shfl_xor(sm, off);
      att_s[tid] = e / sm;
    }
    __syncthreads();
    if (tid < 256) {
      const float4* ctx4 = reinterpret_cast<const float4*>(ctx);
      float4 a4 = {0.f, 0.f, 0.f, 0.f};
      for (int s = 0; s < 64; ++s) {
        float a = att_s[s];
        float4 x = ctx4[(size_t)(s * B_ + b) * 256 + tid];
        a4.x += a * x.x; a4.y += a * x.y; a4.z += a * x.z; a4.w += a * x.w;
      }
#pragma unroll 4
      for (int t = 0; t < T_; ++t)
        reinterpret_cast<float4*>(out + (size_t)(t * B_ + b) * C_)[tid] = a4;
    }
    if (tid < 64) {
      float av = att_s[tid];
#pragma unroll 4
      for (int t = 0; t < T_; ++t) out[OUT_AT + (t * B_ + b) * 64 + tid] = av;
    }
    return;
  }

  // ================= recurrence path (r8 step structure) =================
  int q = w & 3, ks = w >> 2;
  int g = lane >> 4, r = lane & 15;
  int hidx0 = wg * 16 + q * 4;
  int kbase = ks * 256;
  int j = (r >> 2) * 1024 + hidx0 + (r & 3);
  // W_hh fragments: f32 load + in-register bf16 pack
  bf16x8 ah[8];
  {
    const float* ap = Whh + (size_t)j * 1024 + kbase + g * 8;
#pragma unroll
    for (int kk = 0; kk < 8; ++kk) {
      float4 f0 = *reinterpret_cast<const float4*>(ap + kk * 32);
      float4 f1 = *reinterpret_cast<const float4*>(ap + kk * 32 + 4);
      bf16x8 t8;
      t8[0] = (short)f2b(f0.x); t8[1] = (short)f2b(f0.y);
      t8[2] = (short)f2b(f0.z); t8[3] = (short)f2b(f0.w);
      t8[4] = (short)f2b(f1.x); t8[5] = (short)f2b(f1.y);
      t8[6] = (short)f2b(f1.z); t8[7] = (short)f2b(f1.w);
      ah[kk] = t8;
    }
  }
  float c_reg = 0.f;
  int eb = tid & 31, hl = (tid >> 5) & 3, qq = tid >> 7;  // epilogue cell (tid<512)
  int ehidx = wg * 16 + qq * 4 + hl;
  float bs_i = 0.f, bs_f = 0.f, bs_g = 0.f, bs_o = 0.f;
  if (tid < 512) {
    bs_i = bih[ehidx] + bhh[ehidx];
    bs_f = bih[1024 + ehidx] + bhh[1024 + ehidx];
    bs_g = bih[2048 + ehidx] + bhh[2048 + ehidx];
    bs_o = bih[3072 + ehidx] + bhh[3072 + ehidx];
  }
  int cb = ks * 32 + g;

#pragma unroll 1
  for (int t = 0; t < T_; ++t) {
    // ---- poll (w0): h flags (t>0) + xpT slab readiness for step t ----
    if (w == 0) {
      if (t > 0) {
        for (;;) {
          unsigned vfl = __hip_atomic_load(&flags[lane * 16], __ATOMIC_RELAXED, __HIP_MEMORY_SCOPE_AGENT);
          if (__all((int)(vfl >= (unsigned)t))) break;
          __builtin_amdgcn_s_sleep(1);
        }
      }
      for (;;) {
        unsigned xf = __hip_atomic_load(&flags[1024 + t], __ATOMIC_RELAXED, __HIP_MEMORY_SCOPE_AGENT);
        if (__all((int)(xf >= 4u))) break;
        __builtin_amdgcn_s_sleep(1);
      }
    }
    __syncthreads();  // S1
    // prefetch this step's xpT (4 plain cached loads; in flight during staging+MFMA)
    float xv_i = 0.f, xv_f = 0.f, xv_g = 0.f, xv_o = 0.f;
    if (tid < 512) {
      size_t base = (size_t)(t * 32 + eb) * 4096;
      xv_i = b2f(xpT[base + ehidx]);
      xv_f = b2f(xpT[base + 1024 + ehidx]);
      xv_g = b2f(xpT[base + 2048 + ehidx]);
      xv_o = b2f(xpT[base + 3072 + ehidx]);
    }
    // ---- stage h slot t ----
    {
      const uint4* s4 = reinterpret_cast<const uint4*>(hring + (size_t)t * HSLOT);
      uint4 v0 = s4[tid], v1 = s4[tid + 1024], v2 = s4[tid + 2048], v3 = s4[tid + 3072];
      int c0 = tid, c1 = tid + 1024, c2 = tid + 2048, c3 = tid + 3072;
      hl4[(c0 >> 7) * 128 + ((c0 & 127) ^ ((c0 >> 7) & 7))] = v0;
      hl4[(c1 >> 7) * 128 + ((c1 & 127) ^ ((c1 >> 7) & 7))] = v1;
      hl4[(c2 >> 7) * 128 + ((c2 & 127) ^ ((c2 >> 7) & 7))] = v2;
      hl4[(c3 >> 7) * 128 + ((c3 & 127) ^ ((c3 >> 7) & 7))] = v3;
    }
    __syncthreads();  // S2
    f32x4 acc0 = (f32x4)(0.f), acc1 = (f32x4)(0.f);
#pragma unroll
    for (int kk = 0; kk < 8; ++kk) {
      int c16 = cb + kk * 4;
      bf16x8 b0 = *reinterpret_cast<const bf16x8*>(&hl4[r * 128 + (c16 ^ (r & 7))]);
      bf16x8 b1 = *reinterpret_cast<const bf16x8*>(&hl4[(r + 16) * 128 + (c16 ^ (r & 7))]);
      acc0 = __builtin_amdgcn_mfma_f32_16x16x32_bf16(ah[kk], b0, acc0, 0, 0, 0);
      acc1 = __builtin_amdgcn_mfma_f32_16x16x32_bf16(ah[kk], b1, acc1, 0, 0, 0);
    }
#pragma unroll
    for (int e = 0; e < 4; ++e) {
      red[q][ks][g * 4 + e][r] = acc0[e];
      red[q][ks][g * 4 + e][r + 16] = acc1[e];
    }
    __syncthreads();  // S3
    if (tid < 512) {
      float ig = red[qq][0][0 + hl][eb]  + red[qq][1][0 + hl][eb]  + red[qq][2][0 + hl][eb]  + red[qq][3][0 + hl][eb]  + xv_i + bs_i;
      float fg = red[qq][0][4 + hl][eb]  + red[qq][1][4 + hl][eb]  + red[qq][2][4 + hl][eb]  + red[qq][3][4 + hl][eb]  + xv_f + bs_f;
      float gg = red[qq][0][8 + hl][eb]  + red[qq][1][8 + hl][eb]  + red[qq][2][8 + hl][eb]  + red[qq][3][8 + hl][eb]  + xv_g + bs_g;
      float og = red[qq][0][12 + hl][eb] + red[qq][1][12 + hl][eb] + red[qq][2][12 + hl][eb] + red[qq][3][12 + hl][eb] + xv_o + bs_o;
      float si = 1.f / (1.f + __expf(-ig));
      float sf = 1.f / (1.f + __expf(-fg));
      float so = 1.f / (1.f + __expf(-og));
      float c_new = sf * c_reg + si * tanhf(gg);
      float h_new = so * tanhf(c_new);
      c_reg = c_new;
      hs[eb][qq * 4 + hl] = f2b(h_new);
      if (t == T_ - 1) {
        out[OUT_H + eb * 1024 + ehidx] = h_new;
        out[OUT_CC + eb * 1024 + ehidx] = c_new;
      }
    }
    __syncthreads();  // S4: hs ready
    if (t != T_ - 1 && w == 0) {
      ushort* hout = hring + (size_t)(t + 1) * HSLOT;
      int b = lane >> 1, half = lane & 1;
      uint4 vv = *reinterpret_cast<const uint4*>(&hs[b][half * 8]);
      unsigned* hp = reinterpret_cast<unsigned*>(hout) + b * 512 + wg * 8 + half * 4;
      __hip_atomic_store(hp + 0, vv.x, __ATOMIC_RELAXED, __HIP_MEMORY_SCOPE_AGENT);
      __hip_atomic_store(hp + 1, vv.y, __ATOMIC_RELAXED, __HIP_MEMORY_SCOPE_AGENT);
      __hip_atomic_store(hp + 2, vv.z, __ATOMIC_RELAXED, __HIP_MEMORY_SCOPE_AGENT);
      __hip_atomic_store(hp + 3, vv.w, __ATOMIC_RELAXED, __HIP_MEMORY_SCOPE_AGENT);
      asm volatile("s_waitcnt vmcnt(0)" ::: "memory");
      if (lane == 0)
        __hip_atomic_store(&flags[wg * 16], (unsigned)(t + 1), __ATOMIC_RELAXED, __HIP_MEMORY_SCOPE_AGENT);
    }
  }
}

extern "C" void kernel_launch(void* const* d_in, const int* in_sizes, int n_in,
                              void* d_out, int out_size, void* d_ws, size_t ws_size,
                              hipStream_t stream) {
  const float* inp = (const float*)d_in[0];
  const float* ctx = (const float*)d_in[1];
  const float* Wih = (const float*)d_in[2];
  const float* Whh = (const float*)d_in[3];
  const float* bih = (const float*)d_in[4];
  const float* bhh = (const float*)d_in[5];
  const float* W1  = (const float*)d_in[6];
  const float* W2  = (const float*)d_in[8];
  float* out = (float*)d_out;
  char* wsb = (char*)d_ws;

  unsigned* flags = (unsigned*)(wsb + 0);      // 8 KB (h-flags @ i*16, xflags @ 1024+t)
  ushort* inpb  = (ushort*)(wsb + 8192);       // 2 MB
  ushort* Wihb  = (ushort*)(wsb + 2105344);    // 8 MB
  ushort* xpT   = (ushort*)(wsb + 10493952);   // 8 MB [t][b][gate][hid] bf16
  ushort* hring = (ushort*)(wsb + 18882560);   // 33 slots x 64 KB = 2112 KB

  hipLaunchKernelGGL(k_init, dim3(2565), dim3(256), 0, stream, inp, inpb, Wih, Wihb, hring, flags);

  const float* Whh_c = Whh;
  const ushort* Wihb_c = Wihb;
  const ushort* inpb_c = inpb;
  const float* ctx_c = ctx;
  const float* W1_c = W1;
  const float* W2_c = W2;
  const float* bih_c = bih;
  const float* bhh_c = bhh;
  void* kargs[12];
  kargs[0] = (void*)&Whh_c;
  kargs[1] = (void*)&Wihb_c;
  kargs[2] = (void*)&inpb_c;
  kargs[3] = (void*)&hring;
  kargs[4] = (void*)&ctx_c;
  kargs[5] = (void*)&W1_c;
  kargs[6] = (void*)&W2_c;
  kargs[7] = (void*)&bih_c;
  kargs[8] = (void*)&bhh_c;
  kargs[9] = (void*)&out;
  kargs[10] = (void*)&flags;
  kargs[11] = (void*)&xpT;
  hipLaunchCooperativeKernel((const void*)k_rec, dim3(NWG + 32 + 128), dim3(1024), kargs, 0, stream);
}

// Round 20
// 245.635 us; speedup vs baseline: 1.5867x; 1.0990x over previous
//
#include <hip/hip_runtime.h>

#define T_ 32
#define B_ 32
#define S_ 64
#define C_ 1024
#define H_ 1024
#define NWG 64
#define HSLOT 32768  // ushorts per h ring slot / x_t slab

typedef __attribute__((ext_vector_type(8))) short bf16x8;
typedef __attribute__((ext_vector_type(4))) float f32x4;

// d_out layout (float offsets): outputs[32*32*1024], h[32*1024], c[32*1024], attn[32*32*64]
#define OUT_H   1048576
#define OUT_CC  1081344
#define OUT_AT  1114112

__device__ __forceinline__ ushort f2b(float f) {
  unsigned u = __float_as_uint(f);
  unsigned r = (u + 0x7FFFu + ((u >> 16) & 1u)) >> 16;
  return (ushort)r;
}
__device__ __forceinline__ float b2f(ushort h) {
  return __uint_as_float(((unsigned)h) << 16);
}

// ---- init: cvt inp + Wih to bf16; zero hring slot0; zero flags ----
__global__ __launch_bounds__(256) void k_init(const float* __restrict__ inp, ushort* __restrict__ inpb,
                                              const float* __restrict__ Wih, ushort* __restrict__ Wihb,
                                              ushort* __restrict__ hring, unsigned* __restrict__ flags) {
  int blk = blockIdx.x, tid = threadIdx.x;
  if (blk < 2560) {
    const float* src; ushort* dst; int base;
    if (blk < 512) { src = inp; dst = inpb; base = blk; }
    else { src = Wih; dst = Wihb; base = blk - 512; }
    size_t i = ((size_t)base * 256 + tid) * 8;
    float4 v0 = *reinterpret_cast<const float4*>(src + i);
    float4 v1 = *reinterpret_cast<const float4*>(src + i + 4);
    uint4 o;
    o.x = (unsigned)f2b(v0.x) | ((unsigned)f2b(v0.y) << 16);
    o.y = (unsigned)f2b(v0.z) | ((unsigned)f2b(v0.w) << 16);
    o.z = (unsigned)f2b(v1.x) | ((unsigned)f2b(v1.y) << 16);
    o.w = (unsigned)f2b(v1.z) | ((unsigned)f2b(v1.w) << 16);
    *reinterpret_cast<uint4*>(dst + i) = o;
  } else if (blk < 2564) {
    unsigned* hz = reinterpret_cast<unsigned*>(hring);
    int base = (blk - 2560) * 4096;
    for (int i = 0; i < 16; ++i) hz[base + i * 256 + tid] = 0u;
  } else {
    for (int i = 0; i < 8; ++i) flags[i * 256 + tid] = 0u;
  }
}

// ---- cooperative kernel: 224 WGs x 1024 threads ----
// WGs 0..63   : persistent recurrence (r8 step structure; xpT consumed via xflag gating)
// WGs 64..95  : attention (computes v itself) + outputs/attn broadcast; exit
// WGs 96..223 : x-projection producers: WG j -> t=(j-96)>>2, gate=(j-96)&3; publish xpT slab
//               [t][gate][hid][b] via coalesced agent-scope u64 stores + atomicAdd(xflag[t]); exit
__global__ __launch_bounds__(1024, 4) void k_rec(const float* __restrict__ Whh, const ushort* __restrict__ Wihb,
                                                 const ushort* __restrict__ inpb, ushort* __restrict__ hring,
                                                 const float* __restrict__ ctx,
                                                 const float* __restrict__ W1, const float* __restrict__ W2,
                                                 const float* __restrict__ bih, const float* __restrict__ bhh,
                                                 float* __restrict__ out, unsigned* __restrict__ flags,
                                                 ushort* __restrict__ xpT) {
  int tid = threadIdx.x, lane = tid & 63, w = tid >> 6;
  int wg = blockIdx.x;

  __shared__ uint4 hl4[4096];           // 64 KB staging: idx = row*128 + (c16 ^ (row&7))
  __shared__ float red[4][4][16][32];   // 32 KB K-slice partials
  __shared__ __align__(16) ushort hs[32][16];
  __shared__ float v_s[1024];
  __shared__ float sc_s[64];
  __shared__ float att_s[64];

  if (wg >= NWG + 32) {
    // ================= x-projection producer =================
    int j = wg - (NWG + 32);
    int t = j >> 2, gate = j & 3;
    // stage x_t
    {
      const uint4* s4 = reinterpret_cast<const uint4*>(inpb + (size_t)t * HSLOT);
      uint4 v0 = s4[tid], v1 = s4[tid + 1024], v2 = s4[tid + 2048], v3 = s4[tid + 3072];
      int c0 = tid, c1 = tid + 1024, c2 = tid + 2048, c3 = tid + 3072;
      hl4[(c0 >> 7) * 128 + ((c0 & 127) ^ ((c0 >> 7) & 7))] = v0;
      hl4[(c1 >> 7) * 128 + ((c1 & 127) ^ ((c1 >> 7) & 7))] = v1;
      hl4[(c2 >> 7) * 128 + ((c2 & 127) ^ ((c2 >> 7) & 7))] = v2;
      hl4[(c3 >> 7) * 128 + ((c3 & 127) ^ ((c3 >> 7) & 7))] = v3;
    }
    __syncthreads();
    int g = lane >> 4, r = lane & 15;
    f32x4 acc[2][4];
#pragma unroll
    for (int a = 0; a < 2; ++a)
#pragma unroll
      for (int b = 0; b < 4; ++b) acc[a][b] = (f32x4)(0.f);
#pragma unroll 4
    for (int kstep = 0; kstep < 32; ++kstep) {
      int c16 = kstep * 4 + g;
      bf16x8 af0 = *reinterpret_cast<const bf16x8*>(&hl4[r * 128 + (c16 ^ (r & 7))]);
      bf16x8 af1 = *reinterpret_cast<const bf16x8*>(&hl4[(16 + r) * 128 + (c16 ^ (r & 7))]);
#pragma unroll
      for (int hq = 0; hq < 4; ++hq) {
        int hid = w * 64 + hq * 16 + r;
        bf16x8 bw = *reinterpret_cast<const bf16x8*>(Wihb + (size_t)(gate * 1024 + hid) * 1024 + kstep * 32 + g * 8);
        acc[0][hq] = __builtin_amdgcn_mfma_f32_16x16x32_bf16(af0, bw, acc[0][hq], 0, 0, 0);
        acc[1][hq] = __builtin_amdgcn_mfma_f32_16x16x32_bf16(af1, bw, acc[1][hq], 0, 0, 0);
      }
    }
    __syncthreads();  // x reads done; reuse hl4 as bf16 xs[hid(1024)][b(32)]
    {
      ushort* xs = reinterpret_cast<ushort*>(hl4);
      int q = lane >> 4;
#pragma unroll
      for (int bh = 0; bh < 2; ++bh)
#pragma unroll
        for (int hq = 0; hq < 4; ++hq)
#pragma unroll
          for (int e = 0; e < 4; ++e)
            xs[(w * 64 + hq * 16 + r) * 32 + bh * 16 + q * 4 + e] = f2b(acc[bh][hq][e]);
    }
    __syncthreads();
    // coalesced agent-scope publish: thread owns hid = tid; 64B contiguous (8 x u64)
    {
      const unsigned long long* xs8 = reinterpret_cast<const unsigned long long*>(hl4);
      unsigned long long* dst = reinterpret_cast<unsigned long long*>(
          xpT + ((size_t)(t * 4 + gate) * 1024 + tid) * 32);
#pragma unroll
      for (int i = 0; i < 8; ++i) {
        unsigned long long val = xs8[tid * 8 + i];
        __hip_atomic_store(dst + i, val, __ATOMIC_RELAXED, __HIP_MEMORY_SCOPE_AGENT);
      }
    }
    asm volatile("s_waitcnt vmcnt(0)" ::: "memory");
    __syncthreads();
    if (tid == 0)
      __hip_atomic_fetch_add(&flags[1024 + t], 1u, __ATOMIC_RELAXED, __HIP_MEMORY_SCOPE_AGENT);
    return;
  }

  if (wg >= NWG) {
    // ================= attention path (batch b = wg-64) =================
    int b = wg - NWG;
    {
      float acc = 0.f;
#pragma unroll 8
      for (int a = 0; a < 128; ++a) acc += W1[a * 2048 + 1024 + tid] * W2[a];
      v_s[tid] = acc;
    }
    __syncthreads();
    {
      int s = w * 4;
#pragma unroll
      for (int si = 0; si < 4; ++si, ++s) {
        const float* xr = ctx + (size_t)(s * B_ + b) * C_;
        float acc = 0.f;
#pragma unroll
        for (int i = 0; i < 16; ++i) { int c = lane + i * 64; acc += xr[c] * v_s[c]; }
        for (int off = 32; off; off >>= 1) acc += __shfl_down(acc, off);
        if (lane == 0) sc_s[s] = acc;
      }
    }
    __syncthreads();
    if (tid < 64) {
      float val = sc_s[tid];
      float mx = val;
      for (int off = 32; off; off >>= 1) mx = fmaxf(mx, __shfl_xor(mx, off));
      float e = expf(val - mx);
      float sm = e;
      for (int off = 32; off; off >>= 1) sm += __shfl_xor(sm, off);
      att_s[tid] = e / sm;
    }
    __syncthreads();
    if (tid < 256) {
      const float4* ctx4 = reinterpret_cast<const float4*>(ctx);
      float4 a4 = {0.f, 0.f, 0.f, 0.f};
      for (int s = 0; s < 64; ++s) {
        float a = att_s[s];
        float4 x = ctx4[(size_t)(s * B_ + b) * 256 + tid];
        a4.x += a * x.x; a4.y += a * x.y; a4.z += a * x.z; a4.w += a * x.w;
      }
#pragma unroll 4
      for (int t = 0; t < T_; ++t)
        reinterpret_cast<float4*>(out + (size_t)(t * B_ + b) * C_)[tid] = a4;
    }
    if (tid < 64) {
      float av = att_s[tid];
#pragma unroll 4
      for (int t = 0; t < T_; ++t) out[OUT_AT + (t * B_ + b) * 64 + tid] = av;
    }
    return;
  }

  // ================= recurrence path (r8 step structure) =================
  int q = w & 3, ks = w >> 2;
  int g = lane >> 4, r = lane & 15;
  int hidx0 = wg * 16 + q * 4;
  int kbase = ks * 256;
  int j = (r >> 2) * 1024 + hidx0 + (r & 3);
  // W_hh fragments: f32 load + in-register bf16 pack
  bf16x8 ah[8];
  {
    const float* ap = Whh + (size_t)j * 1024 + kbase + g * 8;
#pragma unroll
    for (int kk = 0; kk < 8; ++kk) {
      float4 f0 = *reinterpret_cast<const float4*>(ap + kk * 32);
      float4 f1 = *reinterpret_cast<const float4*>(ap + kk * 32 + 4);
      bf16x8 t8;
      t8[0] = (short)f2b(f0.x); t8[1] = (short)f2b(f0.y);
      t8[2] = (short)f2b(f0.z); t8[3] = (short)f2b(f0.w);
      t8[4] = (short)f2b(f1.x); t8[5] = (short)f2b(f1.y);
      t8[6] = (short)f2b(f1.z); t8[7] = (short)f2b(f1.w);
      ah[kk] = t8;
    }
  }
  float c_reg = 0.f;
  int eb = tid & 31, hl = (tid >> 5) & 3, qq = tid >> 7;  // epilogue cell (tid<512)
  int ehidx = wg * 16 + qq * 4 + hl;
  float bs_i = 0.f, bs_f = 0.f, bs_g = 0.f, bs_o = 0.f;
  if (tid < 512) {
    bs_i = bih[ehidx] + bhh[ehidx];
    bs_f = bih[1024 + ehidx] + bhh[1024 + ehidx];
    bs_g = bih[2048 + ehidx] + bhh[2048 + ehidx];
    bs_o = bih[3072 + ehidx] + bhh[3072 + ehidx];
  }
  int cb = ks * 32 + g;

#pragma unroll 1
  for (int t = 0; t < T_; ++t) {
    // ---- poll (w0): h flags (t>0) + xpT slab readiness for step t ----
    if (w == 0) {
      if (t > 0) {
        for (;;) {
          unsigned vfl = __hip_atomic_load(&flags[lane * 16], __ATOMIC_RELAXED, __HIP_MEMORY_SCOPE_AGENT);
          if (__all((int)(vfl >= (unsigned)t))) break;
          __builtin_amdgcn_s_sleep(1);
        }
      }
      for (;;) {
        unsigned xf = __hip_atomic_load(&flags[1024 + t], __ATOMIC_RELAXED, __HIP_MEMORY_SCOPE_AGENT);
        if (__all((int)(xf >= 4u))) break;
        __builtin_amdgcn_s_sleep(1);
      }
    }
    __syncthreads();  // S1
    // prefetch this step's xpT: [t][gate][hid][b] -> consecutive eb = 64B contiguous per (gate,ehidx)
    float xv_i = 0.f, xv_f = 0.f, xv_g = 0.f, xv_o = 0.f;
    if (tid < 512) {
      size_t base = (size_t)t * 131072 + (size_t)ehidx * 32 + eb;
      xv_i = b2f(xpT[base]);
      xv_f = b2f(xpT[base + 32768]);
      xv_g = b2f(xpT[base + 65536]);
      xv_o = b2f(xpT[base + 98304]);
    }
    // ---- stage h slot t ----
    {
      const uint4* s4 = reinterpret_cast<const uint4*>(hring + (size_t)t * HSLOT);
      uint4 v0 = s4[tid], v1 = s4[tid + 1024], v2 = s4[tid + 2048], v3 = s4[tid + 3072];
      int c0 = tid, c1 = tid + 1024, c2 = tid + 2048, c3 = tid + 3072;
      hl4[(c0 >> 7) * 128 + ((c0 & 127) ^ ((c0 >> 7) & 7))] = v0;
      hl4[(c1 >> 7) * 128 + ((c1 & 127) ^ ((c1 >> 7) & 7))] = v1;
      hl4[(c2 >> 7) * 128 + ((c2 & 127) ^ ((c2 >> 7) & 7))] = v2;
      hl4[(c3 >> 7) * 128 + ((c3 & 127) ^ ((c3 >> 7) & 7))] = v3;
    }
    __syncthreads();  // S2
    f32x4 acc0 = (f32x4)(0.f), acc1 = (f32x4)(0.f);
#pragma unroll
    for (int kk = 0; kk < 8; ++kk) {
      int c16 = cb + kk * 4;
      bf16x8 b0 = *reinterpret_cast<const bf16x8*>(&hl4[r * 128 + (c16 ^ (r & 7))]);
      bf16x8 b1 = *reinterpret_cast<const bf16x8*>(&hl4[(r + 16) * 128 + (c16 ^ (r & 7))]);
      acc0 = __builtin_amdgcn_mfma_f32_16x16x32_bf16(ah[kk], b0, acc0, 0, 0, 0);
      acc1 = __builtin_amdgcn_mfma_f32_16x16x32_bf16(ah[kk], b1, acc1, 0, 0, 0);
    }
#pragma unroll
    for (int e = 0; e < 4; ++e) {
      red[q][ks][g * 4 + e][r] = acc0[e];
      red[q][ks][g * 4 + e][r + 16] = acc1[e];
    }
    __syncthreads();  // S3
    if (tid < 512) {
      float ig = red[qq][0][0 + hl][eb]  + red[qq][1][0 + hl][eb]  + red[qq][2][0 + hl][eb]  + red[qq][3][0 + hl][eb]  + xv_i + bs_i;
      float fg = red[qq][0][4 + hl][eb]  + red[qq][1][4 + hl][eb]  + red[qq][2][4 + hl][eb]  + red[qq][3][4 + hl][eb]  + xv_f + bs_f;
      float gg = red[qq][0][8 + hl][eb]  + red[qq][1][8 + hl][eb]  + red[qq][2][8 + hl][eb]  + red[qq][3][8 + hl][eb]  + xv_g + bs_g;
      float og = red[qq][0][12 + hl][eb] + red[qq][1][12 + hl][eb] + red[qq][2][12 + hl][eb] + red[qq][3][12 + hl][eb] + xv_o + bs_o;
      float si = 1.f / (1.f + __expf(-ig));
      float sf = 1.f / (1.f + __expf(-fg));
      float so = 1.f / (1.f + __expf(-og));
      float c_new = sf * c_reg + si * tanhf(gg);
      float h_new = so * tanhf(c_new);
      c_reg = c_new;
      hs[eb][qq * 4 + hl] = f2b(h_new);
      if (t == T_ - 1) {
        out[OUT_H + eb * 1024 + ehidx] = h_new;
        out[OUT_CC + eb * 1024 + ehidx] = c_new;
      }
    }
    __syncthreads();  // S4: hs ready
    if (t != T_ - 1 && w == 0) {
      ushort* hout = hring + (size_t)(t + 1) * HSLOT;
      int b = lane >> 1, half = lane & 1;
      uint4 vv = *reinterpret_cast<const uint4*>(&hs[b][half * 8]);
      unsigned* hp = reinterpret_cast<unsigned*>(hout) + b * 512 + wg * 8 + half * 4;
      __hip_atomic_store(hp + 0, vv.x, __ATOMIC_RELAXED, __HIP_MEMORY_SCOPE_AGENT);
      __hip_atomic_store(hp + 1, vv.y, __ATOMIC_RELAXED, __HIP_MEMORY_SCOPE_AGENT);
      __hip_atomic_store(hp + 2, vv.z, __ATOMIC_RELAXED, __HIP_MEMORY_SCOPE_AGENT);
      __hip_atomic_store(hp + 3, vv.w, __ATOMIC_RELAXED, __HIP_MEMORY_SCOPE_AGENT);
      asm volatile("s_waitcnt vmcnt(0)" ::: "memory");
      if (lane == 0)
        __hip_atomic_store(&flags[wg * 16], (unsigned)(t + 1), __ATOMIC_RELAXED, __HIP_MEMORY_SCOPE_AGENT);
    }
  }
}

extern "C" void kernel_launch(void* const* d_in, const int* in_sizes, int n_in,
                              void* d_out, int out_size, void* d_ws, size_t ws_size,
                              hipStream_t stream) {
  const float* inp = (const float*)d_in[0];
  const float* ctx = (const float*)d_in[1];
  const float* Wih = (const float*)d_in[2];
  const float* Whh = (const float*)d_in[3];
  const float* bih = (const float*)d_in[4];
  const float* bhh = (const float*)d_in[5];
  const float* W1  = (const float*)d_in[6];
  const float* W2  = (const float*)d_in[8];
  float* out = (float*)d_out;
  char* wsb = (char*)d_ws;

  unsigned* flags = (unsigned*)(wsb + 0);      // 8 KB (h-flags @ i*16, xflags @ 1024+t)
  ushort* inpb  = (ushort*)(wsb + 8192);       // 2 MB
  ushort* Wihb  = (ushort*)(wsb + 2105344);    // 8 MB
  ushort* xpT   = (ushort*)(wsb + 10493952);   // 8 MB [t][gate][hid][b] bf16
  ushort* hring = (ushort*)(wsb + 18882560);   // 33 slots x 64 KB = 2112 KB

  hipLaunchKernelGGL(k_init, dim3(2565), dim3(256), 0, stream, inp, inpb, Wih, Wihb, hring, flags);

  const float* Whh_c = Whh;
  const ushort* Wihb_c = Wihb;
  const ushort* inpb_c = inpb;
  const float* ctx_c = ctx;
  const float* W1_c = W1;
  const float* W2_c = W2;
  const float* bih_c = bih;
  const float* bhh_c = bhh;
  void* kargs[12];
  kargs[0] = (void*)&Whh_c;
  kargs[1] = (void*)&Wihb_c;
  kargs[2] = (void*)&inpb_c;
  kargs[3] = (void*)&hring;
  kargs[4] = (void*)&ctx_c;
  kargs[5] = (void*)&W1_c;
  kargs[6] = (void*)&W2_c;
  kargs[7] = (void*)&bih_c;
  kargs[8] = (void*)&bhh_c;
  kargs[9] = (void*)&out;
  kargs[10] = (void*)&flags;
  kargs[11] = (void*)&xpT;
  hipLaunchCooperativeKernel((const void*)k_rec, dim3(NWG + 32 + 128), dim3(1024), kargs, 0, stream);
}